// Round 1
// baseline (101.913 us; speedup 1.0000x reference)
//
#include <hip/hip_runtime.h>

// BoundaryLoss: exact separable squared EDT per (b,k,which) plane-mask,
// fused with x*dist contraction into a single f32 scalar mean.
//
// Shapes: x (8,4,256,256) f32; y (8,1,256,256) i32 labels in [0,4).
// Output: scalar f32 = mean(x * dist_map).
//
// dist_map per plane: at neg pixels  +d(pos), at pos pixels  -(d(neg)-1) = (1-d(neg)).
// All squared distances are exact integers (<= 130050), matching the
// reference's f32 brute-force min bit-for-bit after sqrtf.

#define HH 256
#define WW 256
#define NPIX (HH*WW)        // 65536
#define NPM 64              // 8 b * 4 k * 2 which
#define NBLK2 1024          // kernel-2 grid
#define ROWS_PER_BLK 16
#define BIG (1 << 27)       // sentinel for "no feature" (beats 0xFFFF u16)

// ---------------- Kernel 1: vertical pass (per-column nearest feature) -----
// grid: 256 blocks (pm*4 + colchunk), 64 threads (1 wave), thread = column.
__global__ void edt_vpass(const int* __restrict__ y, unsigned short* __restrict__ g) {
    int pm    = blockIdx.x >> 2;        // plane-mask id 0..63
    int chunk = blockIdx.x & 3;
    int w     = chunk * 64 + threadIdx.x;
    int which = pm & 1;                 // 0: feature = (y==k), 1: feature = (y!=k)
    int plane = pm >> 1;                // 0..31
    int b     = plane >> 2;
    int k     = plane & 3;

    const int* yp = y + b * NPIX;
    unsigned short* gp = g + (size_t)pm * NPIX;

    // forward scan: distance to nearest feature above (or big)
    int last = -300;
    for (int h = 0; h < HH; ++h) {
        int lab  = yp[h * WW + w];              // coalesced across lanes
        int feat = ((lab == k) ? 1 : 0) ^ which;
        if (feat) last = h;
        gp[h * WW + w] = (unsigned short)(h - last);   // <= 555, fits u16
    }
    // backward scan: combine with distance to nearest feature below; square.
    int nd = 600;
    for (int h = HH - 1; h >= 0; --h) {
        int du = gp[h * WW + w];                // same-thread readback, L2-hot
        nd = (du == 0) ? 0 : min(nd + 1, 600);
        int m = min(du, nd);
        gp[h * WW + w] = (m > 255) ? (unsigned short)0xFFFF
                                   : (unsigned short)(m * m);   // <= 65025
    }
}

// ---------------- Kernel 2: horizontal pass + fused contraction ------------
// grid: 64 pm * 16 row-chunks = 1024 blocks, 256 threads (thread = column w).
// Pruned exact search: min_j g[j]+(w-j)^2, expanding r until r^2 >= best.
__global__ void edt_hpass(const unsigned short* __restrict__ g,
                          const float* __restrict__ x,
                          double* __restrict__ bsums) {
    __shared__ unsigned short tile[ROWS_PER_BLK][WW];
    __shared__ double wsum[4];

    int bid   = blockIdx.x;
    int pm    = bid >> 4;
    int rc    = bid & 15;
    int r0    = rc * ROWS_PER_BLK;
    int which = pm & 1;
    int plane = pm >> 1;
    int t     = threadIdx.x;   // = w

    const unsigned short* gp = g + (size_t)pm * NPIX;
    const float* xp = x + (size_t)plane * NPIX;

    for (int i = 0; i < ROWS_PER_BLK; ++i)
        tile[i][t] = gp[(r0 + i) * WW + t];
    __syncthreads();

    double lsum = 0.0;
    for (int i = 0; i < ROWS_PER_BLK; ++i) {
        int gc = tile[i][t];
        int best = (gc == 0xFFFF) ? BIG : gc;
        for (int r = 1; r < WW; ++r) {
            int rr = r * r;
            if (rr >= best) break;      // lossless pruning: g >= 0
            int jl = t - r, jr = t + r;
            if (jl >= 0) {
                int gv = tile[i][jl];
                int c = ((gv == 0xFFFF) ? BIG : gv) + rr;
                best = min(best, c);
            }
            if (jr < WW) {
                int gv = tile[i][jr];
                int c = ((gv == 0xFFFF) ? BIG : gv) + rr;
                best = min(best, c);
            }
        }
        // best==0  -> feature pixel, contributes 0 for this 'which'
        // best>=BIG-> class (or complement) absent: matches has_pos zeroing
        if (best > 0 && best < BIG) {
            float xv   = xp[(r0 + i) * WW + t];
            float d    = sqrtf((float)best);             // correctly rounded
            float term = which ? (1.0f - d) : d;         // == -(d-1) exactly
            lsum += (double)(xv * term);                 // f32 product, f64 acc
        }
    }

    // block reduction (deterministic): wave shuffle, then 4 wave leaders
    for (int off = 32; off > 0; off >>= 1)
        lsum += __shfl_down(lsum, off, 64);
    int lane = t & 63, wv = t >> 6;
    if (lane == 0) wsum[wv] = lsum;
    __syncthreads();
    if (t == 0) bsums[bid] = wsum[0] + wsum[1] + wsum[2] + wsum[3];
}

// ---------------- Kernel 3: final reduce + mean ----------------------------
__global__ void edt_finalize(const double* __restrict__ bsums, float* __restrict__ out) {
    __shared__ double wsum[4];
    int t = threadIdx.x;
    double s = 0.0;
    for (int i = t; i < NBLK2; i += 256) s += bsums[i];
    for (int off = 32; off > 0; off >>= 1)
        s += __shfl_down(s, off, 64);
    int lane = t & 63, wv = t >> 6;
    if (lane == 0) wsum[wv] = s;
    __syncthreads();
    if (t == 0)
        out[0] = (float)((wsum[0] + wsum[1] + wsum[2] + wsum[3]) * (1.0 / 2097152.0));
}

extern "C" void kernel_launch(void* const* d_in, const int* in_sizes, int n_in,
                              void* d_out, int out_size, void* d_ws, size_t ws_size,
                              hipStream_t stream) {
    const float* x = (const float*)d_in[0];
    const int*   y = (const int*)d_in[1];
    float* out = (float*)d_out;

    // workspace layout: [0, 8MB) u16 g planes; [8MB, 8MB+8KB) f64 block sums
    unsigned short* g = (unsigned short*)d_ws;
    double* bsums = (double*)((char*)d_ws + (size_t)NPM * NPIX * sizeof(unsigned short));

    edt_vpass   <<<256,   64, 0, stream>>>(y, g);
    edt_hpass   <<<NBLK2, 256, 0, stream>>>(g, x, bsums);
    edt_finalize<<<1,     256, 0, stream>>>(bsums, out);
}

// Round 2
// 80.790 us; speedup vs baseline: 1.2615x; 1.2615x over previous
//
#include <hip/hip_runtime.h>

// BoundaryLoss: exact separable squared EDT per (b,k,which) plane-mask,
// fused with x*dist contraction into a single f32 scalar mean.
//
// Shapes: x (8,4,256,256) f32; y (8,1,256,256) i32 labels in [0,4).
// Output: scalar f32 = mean(x * dist_map).
//
// dist_map per plane: at neg pixels  +d(pos), at pos pixels  -(d(neg)-1) = (1-d(neg)).
// All squared distances are exact integers (<= 130050), so sqrtf + f32 mul +
// f64 accumulation reproduces the np reference to ~1e-10.

#define HH 256
#define WW 256
#define NPIX (HH*WW)        // 65536
#define NPM 64              // 8 b * 4 k * 2 which
#define NBLK2 1024          // kernel-2 grid
#define ROWS_PER_BLK 16
#define BIG (1 << 27)       // sentinel for "no feature" (beats 0xFFFF u16)

// ---------------- Kernel 1: vertical pass (segmented column scan) ----------
// grid: 64 pm * 8 col-chunks = 512 blocks, 256 threads.
// thread = (segment 0..7) x (local col 0..31); each scans 32 rows of 1 column.
// Segmented scan: local fwd distances -> LDS; per-segment first/last feature
// summaries -> LDS; one sync; cross-segment prefix fixup; backward scan in
// LDS; emit final min^2 as u16 straight to global (no global round-trip).
#define SEGS 8
#define RSEG 32
#define CPB 32

__global__ void edt_vpass(const int* __restrict__ y, unsigned short* __restrict__ g) {
    __shared__ unsigned short d[HH][CPB + 1];   // +1 pad: wave halves hit disjoint bank sets
    __shared__ short segLast[SEGS][CPB];        // last feature row in segment (-1000 if none)
    __shared__ short segFirst[SEGS][CPB];       // first feature row in segment (+1000 if none)

    int bid   = blockIdx.x;
    int pm    = bid >> 3;               // 0..63
    int cc    = bid & 7;                // col chunk
    int which = pm & 1;                 // 0: feature = (y==k), 1: feature = (y!=k)
    int plane = pm >> 1;
    int b     = plane >> 2;
    int k     = plane & 3;

    int t   = threadIdx.x;
    int col = t & (CPB - 1);
    int seg = t >> 5;
    int w   = cc * CPB + col;
    int h0  = seg * RSEG;

    const int* yp = y + b * NPIX;
    unsigned short* gp = g + (size_t)pm * NPIX;

    // forward (downward) local scan
    int lastL = -1000, firstL = 1000;
    for (int i = 0; i < RSEG; ++i) {
        int h   = h0 + i;
        int lab = yp[h * WW + w];                     // 128B chunks per 32 lanes
        int feat = ((lab == k) ? 1 : 0) ^ which;
        if (feat) { lastL = h; if (firstL > 900) firstL = h; }
        d[h][col] = (unsigned short)min(h - lastL, 1000);
    }
    segLast[seg][col]  = (short)lastL;
    segFirst[seg][col] = (short)firstL;
    __syncthreads();

    // cross-segment prefix: nearest feature above my segment / below my segment
    int prevLast = -1000;
    for (int s = seg - 1; s >= 0; --s) {
        int v = segLast[s][col];
        if (v >= 0) { prevLast = v; break; }
    }
    int nextFirst = 1000;
    for (int s = seg + 1; s < SEGS; ++s) {
        int v = segFirst[s][col];
        if (v < 900) { nextFirst = v; break; }
    }

    // backward scan + combine + square + store
    int nd = nextFirst;                               // nearest feature row >= h (so far)
    for (int i = RSEG - 1; i >= 0; --i) {
        int h  = h0 + i;
        int du = d[h][col];
        if (du == 0) nd = h;                          // d==0 marks a feature pixel
        int dup = min(du, h - prevLast);              // true upward distance
        int ddn = nd - h;                             // true downward distance
        int m   = min(min(dup, ddn), 256);
        gp[h * WW + w] = (m > 255) ? (unsigned short)0xFFFF
                                   : (unsigned short)(m * m);   // <= 65025
    }
}

// ---------------- Kernel 2: horizontal pass + fused contraction ------------
// grid: 64 pm * 16 row-chunks = 1024 blocks, 256 threads (thread = column w).
// Pruned exact search: min_j g[j]+(w-j)^2, expanding r until r^2 >= best.
__global__ void edt_hpass(const unsigned short* __restrict__ g,
                          const float* __restrict__ x,
                          double* __restrict__ bsums) {
    __shared__ unsigned short tile[ROWS_PER_BLK][WW];
    __shared__ double wsum[4];

    int bid   = blockIdx.x;
    int pm    = bid >> 4;
    int rc    = bid & 15;
    int r0    = rc * ROWS_PER_BLK;
    int which = pm & 1;
    int plane = pm >> 1;
    int t     = threadIdx.x;   // = w

    const unsigned short* gp = g + (size_t)pm * NPIX;
    const float* xp = x + (size_t)plane * NPIX;

    for (int i = 0; i < ROWS_PER_BLK; ++i)
        tile[i][t] = gp[(r0 + i) * WW + t];
    __syncthreads();

    double lsum = 0.0;
    for (int i = 0; i < ROWS_PER_BLK; ++i) {
        int gc = tile[i][t];
        int best = (gc == 0xFFFF) ? BIG : gc;
        for (int r = 1; r < WW; ++r) {
            int rr = r * r;
            if (rr >= best) break;      // lossless pruning: g >= 0
            int jl = t - r, jr = t + r;
            if (jl >= 0) {
                int gv = tile[i][jl];
                int c = ((gv == 0xFFFF) ? BIG : gv) + rr;
                best = min(best, c);
            }
            if (jr < WW) {
                int gv = tile[i][jr];
                int c = ((gv == 0xFFFF) ? BIG : gv) + rr;
                best = min(best, c);
            }
        }
        // best==0  -> feature pixel, contributes 0 for this 'which'
        // best>=BIG-> class (or complement) absent: matches has_pos zeroing
        if (best > 0 && best < BIG) {
            float xv   = xp[(r0 + i) * WW + t];
            float d    = sqrtf((float)best);             // correctly rounded
            float term = which ? (1.0f - d) : d;         // == -(d-1) exactly
            lsum += (double)(xv * term);                 // f32 product, f64 acc
        }
    }

    // block reduction (deterministic): wave shuffle, then 4 wave leaders
    for (int off = 32; off > 0; off >>= 1)
        lsum += __shfl_down(lsum, off, 64);
    int lane = t & 63, wv = t >> 6;
    if (lane == 0) wsum[wv] = lsum;
    __syncthreads();
    if (t == 0) bsums[bid] = wsum[0] + wsum[1] + wsum[2] + wsum[3];
}

// ---------------- Kernel 3: final reduce + mean ----------------------------
__global__ void edt_finalize(const double* __restrict__ bsums, float* __restrict__ out) {
    __shared__ double wsum[4];
    int t = threadIdx.x;
    double s = 0.0;
    for (int i = t; i < NBLK2; i += 256) s += bsums[i];
    for (int off = 32; off > 0; off >>= 1)
        s += __shfl_down(s, off, 64);
    int lane = t & 63, wv = t >> 6;
    if (lane == 0) wsum[wv] = s;
    __syncthreads();
    if (t == 0)
        out[0] = (float)((wsum[0] + wsum[1] + wsum[2] + wsum[3]) * (1.0 / 2097152.0));
}

extern "C" void kernel_launch(void* const* d_in, const int* in_sizes, int n_in,
                              void* d_out, int out_size, void* d_ws, size_t ws_size,
                              hipStream_t stream) {
    const float* x = (const float*)d_in[0];
    const int*   y = (const int*)d_in[1];
    float* out = (float*)d_out;

    // workspace layout: [0, 8MB) u16 g planes; [8MB, 8MB+8KB) f64 block sums
    unsigned short* g = (unsigned short*)d_ws;
    double* bsums = (double*)((char*)d_ws + (size_t)NPM * NPIX * sizeof(unsigned short));

    edt_vpass   <<<512,   256, 0, stream>>>(y, g);
    edt_hpass   <<<NBLK2, 256, 0, stream>>>(g, x, bsums);
    edt_finalize<<<1,     256, 0, stream>>>(bsums, out);
}

// Round 4
// 78.894 us; speedup vs baseline: 1.2918x; 1.0240x over previous
//
#include <hip/hip_runtime.h>

// BoundaryLoss: exact separable squared EDT per (b,k,which) plane-mask,
// fused with x*dist contraction into a single f32 scalar mean.
//
// Shapes: x (8,4,256,256) f32; y (8,1,256,256) i32 labels in [0,4).
// Output: scalar f32 = mean(x * dist_map).
//
// dist_map per plane: at neg pixels  +d(pos), at pos pixels  -(d(neg)-1) = (1-d(neg)).
// All squared distances are exact integers (<= 130050), so sqrtf + f32 mul +
// f64 accumulation reproduces the np reference to ~1e-10 (measured absmax 0.0).

#define HH 256
#define WW 256
#define NPIX (HH*WW)        // 65536
#define NPM 64              // 8 b * 4 k * 2 which
#define NBLK2 1024          // kernel-2 grid
#define ROWS_PER_BLK 16
#define BIG (1 << 27)       // sentinel for "no feature" (beats any real m^2)

// ---------------- Kernel 1: vertical pass (segmented column scan) ----------
// grid: 64 pm * 8 col-chunks = 512 blocks, 256 threads.
// thread = (segment 0..7) x (local col 0..31); each scans 32 rows of 1 column.
#define SEGS 8
#define RSEG 32
#define CPB 32

__global__ void edt_vpass(const int* __restrict__ y, unsigned short* __restrict__ g) {
    __shared__ unsigned short d[HH][CPB + 1];   // +1 pad
    __shared__ short segLast[SEGS][CPB];        // last feature row in segment (-1000 if none)
    __shared__ short segFirst[SEGS][CPB];       // first feature row in segment (+1000 if none)

    int bid   = blockIdx.x;
    int pm    = bid >> 3;               // 0..63
    int cc    = bid & 7;                // col chunk
    int which = pm & 1;                 // 0: feature = (y==k), 1: feature = (y!=k)
    int plane = pm >> 1;
    int b     = plane >> 2;
    int k     = plane & 3;

    int t   = threadIdx.x;
    int col = t & (CPB - 1);
    int seg = t >> 5;
    int w   = cc * CPB + col;
    int h0  = seg * RSEG;

    const int* yp = y + b * NPIX;
    unsigned short* gp = g + (size_t)pm * NPIX;

    // forward (downward) local scan
    int lastL = -1000, firstL = 1000;
    for (int i = 0; i < RSEG; ++i) {
        int h   = h0 + i;
        int lab = yp[h * WW + w];
        int feat = ((lab == k) ? 1 : 0) ^ which;
        if (feat) { lastL = h; if (firstL > 900) firstL = h; }
        d[h][col] = (unsigned short)min(h - lastL, 1000);
    }
    segLast[seg][col]  = (short)lastL;
    segFirst[seg][col] = (short)firstL;
    __syncthreads();

    // cross-segment prefix: nearest feature above / below my segment
    int prevLast = -1000;
    for (int s = seg - 1; s >= 0; --s) {
        int v = segLast[s][col];
        if (v >= 0) { prevLast = v; break; }
    }
    int nextFirst = 1000;
    for (int s = seg + 1; s < SEGS; ++s) {
        int v = segFirst[s][col];
        if (v < 900) { nextFirst = v; break; }
    }

    // backward scan + combine + square + store
    int nd = nextFirst;
    for (int i = RSEG - 1; i >= 0; --i) {
        int h  = h0 + i;
        int du = d[h][col];
        if (du == 0) nd = h;
        int dup = min(du, h - prevLast);
        int ddn = nd - h;
        int m   = min(min(dup, ddn), 256);
        gp[h * WW + w] = (m > 255) ? (unsigned short)0xFFFF
                                   : (unsigned short)(m * m);   // <= 65025
    }
}

// ---------------- Kernel 2: horizontal pass + fused contraction ------------
// grid: 64 pm * 16 row-chunks = 1024 blocks, 256 threads (thread = column w).
// Batched pruned exact search: min_j g[j]+(w-j)^2. Radii processed 4 at a
// time (8 LDS loads issued together -> latency overlapped); prune check once
// per batch (lossless: all |w-j| >= bs have candidate >= bs^2 >= best).
// Out-of-range cols clamp to 0/255: clamped candidate tile[0]+r^2 with r>w is
// >= tile[0]+w^2, a true candidate already seen at radius w < bs — exact.
__global__ void edt_hpass(const unsigned short* __restrict__ g,
                          const float* __restrict__ x,
                          double* __restrict__ bsums) {
    __shared__ int tile[ROWS_PER_BLK][WW];   // sentinel pre-mapped to BIG
    __shared__ double wsum[4];

    int bid   = blockIdx.x;
    int pm    = bid >> 4;
    int rc    = bid & 15;
    int r0    = rc * ROWS_PER_BLK;
    int which = pm & 1;
    int plane = pm >> 1;
    int t     = threadIdx.x;   // = w

    const unsigned short* gp = g + (size_t)pm * NPIX;
    const float* xp = x + (size_t)plane * NPIX;

    // tile fill: uint loads (2 px each); 16 rows * 128 uints = 2048 = 8*256
    const unsigned int* gp32 = (const unsigned int*)(gp + r0 * WW);
    for (int i2 = 0; i2 < 8; ++i2) {
        int idx = i2 * 256 + t;
        int row = idx >> 7;          // /128
        int c2  = idx & 127;
        unsigned int v = gp32[row * 128 + c2];
        int v0 = (int)(v & 0xFFFFu);
        int v1 = (int)(v >> 16);
        tile[row][2 * c2]     = (v0 == 0xFFFF) ? BIG : v0;
        tile[row][2 * c2 + 1] = (v1 == 0xFFFF) ? BIG : v1;
    }
    __syncthreads();

    double lsum = 0.0;
    for (int i = 0; i < ROWS_PER_BLK; ++i) {
        int best = tile[i][t];
        #pragma unroll 1
        for (int bs = 1; bs < WW; bs += 4) {
            if (bs * bs >= best) break;          // lossless prune
            int m = best;
            #pragma unroll
            for (int u = 0; u < 4; ++u) {
                int r  = bs + u;
                int rr = r * r;
                int jl = max(t - r, 0);
                int jr = min(t + r, WW - 1);
                m = min(m, tile[i][jl] + rr);
                m = min(m, tile[i][jr] + rr);
            }
            best = m;
        }
        // best==0  -> feature pixel, contributes 0 for this 'which'
        // best>=BIG-> class (or complement) absent: matches has_pos zeroing
        if (best > 0 && best < BIG) {
            float xv   = xp[(r0 + i) * WW + t];
            float dd   = sqrtf((float)best);             // exact-int sqrt
            float term = which ? (1.0f - dd) : dd;       // == -(d-1) exactly
            lsum += (double)(xv * term);                 // f32 product, f64 acc
        }
    }

    // block reduction (deterministic): wave shuffle, then 4 wave leaders
    for (int off = 32; off > 0; off >>= 1)
        lsum += __shfl_down(lsum, off, 64);
    int lane = t & 63, wv = t >> 6;
    if (lane == 0) wsum[wv] = lsum;
    __syncthreads();
    if (t == 0) bsums[bid] = wsum[0] + wsum[1] + wsum[2] + wsum[3];
}

// ---------------- Kernel 3: final reduce + mean ----------------------------
__global__ void edt_finalize(const double* __restrict__ bsums, float* __restrict__ out) {
    __shared__ double wsum[4];
    int t = threadIdx.x;
    double s = 0.0;
    for (int i = t; i < NBLK2; i += 256) s += bsums[i];
    for (int off = 32; off > 0; off >>= 1)
        s += __shfl_down(s, off, 64);
    int lane = t & 63, wv = t >> 6;
    if (lane == 0) wsum[wv] = s;
    __syncthreads();
    if (t == 0)
        out[0] = (float)((wsum[0] + wsum[1] + wsum[2] + wsum[3]) * (1.0 / 2097152.0));
}

extern "C" void kernel_launch(void* const* d_in, const int* in_sizes, int n_in,
                              void* d_out, int out_size, void* d_ws, size_t ws_size,
                              hipStream_t stream) {
    const float* x = (const float*)d_in[0];
    const int*   y = (const int*)d_in[1];
    float* out = (float*)d_out;

    // workspace layout: [0, 8MB) u16 g planes; [8MB, 8MB+8KB) f64 block sums
    unsigned short* g = (unsigned short*)d_ws;
    double* bsums = (double*)((char*)d_ws + (size_t)NPM * NPIX * sizeof(unsigned short));

    edt_vpass   <<<512,   256, 0, stream>>>(y, g);
    edt_hpass   <<<NBLK2, 256, 0, stream>>>(g, x, bsums);
    edt_finalize<<<1,     256, 0, stream>>>(bsums, out);
}